// Round 4
// baseline (146.544 us; speedup 1.0000x reference)
//
#include <hip/hip_runtime.h>
#include <math.h>

#define N 4096
#define D 768
#define MARGIN 1.0f
#define NBLK 576   // 512 full 128x128 tiles + 16 tiles split into 4x(128x32)

typedef _Float16 half8 __attribute__((ext_vector_type(8)));
typedef _Float16 half4 __attribute__((ext_vector_type(4)));
typedef float f32x4 __attribute__((ext_vector_type(4)));

__device__ __forceinline__ void gl2lds16(const void* g, void* l) {
    __builtin_amdgcn_global_load_lds((const __attribute__((address_space(1))) void*)g,
                                     (__attribute__((address_space(3))) void*)l, 16, 0, 0);
}

// ---------------- Kernel 1: row L2-normalize (wave-per-row) + init ----------
__global__ __launch_bounds__(256) void normalize_kernel(const float* __restrict__ x,
                                                        _Float16* __restrict__ e,
                                                        float* __restrict__ sq,
                                                        unsigned* __restrict__ ap_bits,
                                                        unsigned* __restrict__ an_bits,
                                                        unsigned* __restrict__ counter) {
    const int tid = threadIdx.x;
    const int wave = tid >> 6, lane = tid & 63;
    const int row = blockIdx.x * 4 + wave;

    const float4* xr = (const float4*)(x + (size_t)row * D);   // 192 float4/row
    float4 f0 = xr[lane];
    float4 f1 = xr[lane + 64];
    float4 f2 = xr[lane + 128];

    float s = f0.x*f0.x + f0.y*f0.y + f0.z*f0.z + f0.w*f0.w
            + f1.x*f1.x + f1.y*f1.y + f1.z*f1.z + f1.w*f1.w
            + f2.x*f2.x + f2.y*f2.y + f2.z*f2.z + f2.w*f2.w;
    #pragma unroll
    for (int off = 1; off < 64; off <<= 1) s += __shfl_xor(s, off, 64);

    float scale = 1.0f / fmaxf(sqrtf(s), 1e-12f);

    half4* er = (half4*)(e + (size_t)row * D);
    half4 h0 = { (_Float16)(f0.x*scale), (_Float16)(f0.y*scale), (_Float16)(f0.z*scale), (_Float16)(f0.w*scale) };
    half4 h1 = { (_Float16)(f1.x*scale), (_Float16)(f1.y*scale), (_Float16)(f1.z*scale), (_Float16)(f1.w*scale) };
    half4 h2 = { (_Float16)(f2.x*scale), (_Float16)(f2.y*scale), (_Float16)(f2.z*scale), (_Float16)(f2.w*scale) };
    er[lane]       = h0;
    er[lane + 64]  = h1;
    er[lane + 128] = h2;

    if (lane == 0) {
        sq[row] = s * scale * scale;
        ap_bits[row] = 0u;                 // float 0.0  (max init)
        an_bits[row] = 0x7f800000u;        // +inf       (min init)
    }
    if (blockIdx.x == 0 && tid == 0) *counter = 0u;
}

// ---------------- templated tile worker (BK=64, single-buffered) -----------
// MTN x NTN MFMA tiles per wave; BROWS = rows of B staged (128 or 32).
// LDS: A = S[0..8191] ushorts (128 rows x 64 halves, XOR-swizzled),
//      B = S[8192..]  ushorts (BROWS rows x 64 halves).
template<int MTN, int NTN, int BROWS>
__device__ __forceinline__ void tile_work(const _Float16* __restrict__ e,
                                          const float* __restrict__ sq,
                                          const int* __restrict__ labels,
                                          unsigned* __restrict__ ap_bits,
                                          unsigned* __restrict__ an_bits,
                                          unsigned short* S,
                                          int i0, int j0, int joff,
                                          int wi, int wjL,
                                          int tid, int w, int lane, bool diag) {
    const int ln15 = lane & 15;
    const int lq   = lane >> 4;       // 0..3
    const int rk   = ln15 & 7;        // row-dependent swizzle key for fragment reads

    f32x4 acc[MTN][NTN] = {};

    for (int kt = 0; kt < 12; ++kt) {
        const int k0 = kt * 64;
        __syncthreads();              // protect LDS from previous iteration's readers
        // stage A: 128 rows x 8 granules (16B) = 1024 granules, 4 per thread
        #pragma unroll
        for (int p = 0; p < 4; ++p) {
            int s  = p * 256 + tid;
            int r  = s >> 3;
            int g  = (s & 7) ^ (r & 7);           // data granule g lands at position s&7
            gl2lds16(e + (size_t)(i0 + r) * D + k0 + g * 8,
                     (char*)S + (p * 256 + w * 64) * 16);
        }
        // stage B: BROWS rows x 8 granules
        #pragma unroll
        for (int p = 0; p < BROWS / 32; ++p) {
            int s  = p * 256 + tid;
            int r  = s >> 3;
            int g  = (s & 7) ^ (r & 7);
            gl2lds16(e + (size_t)(j0 + joff + r) * D + k0 + g * 8,
                     (char*)S + 16384 + (p * 256 + w * 64) * 16);
        }
        __syncthreads();

        #pragma unroll
        for (int c = 0; c < 2; ++c) {
            const int kx = (c * 4 + lq) ^ rk;     // swizzled granule within row
            half8 af[MTN], bf[NTN];
            #pragma unroll
            for (int mt = 0; mt < MTN; ++mt) {
                int r = wi + mt * 16 + ln15;
                af[mt] = *(const half8*)&S[r * 64 + kx * 8];
            }
            #pragma unroll
            for (int nt = 0; nt < NTN; ++nt) {
                int r = wjL + nt * 16 + ln15;
                bf[nt] = *(const half8*)&S[8192 + r * 64 + kx * 8];
            }
            #pragma unroll
            for (int mt = 0; mt < MTN; ++mt)
                #pragma unroll
                for (int nt = 0; nt < NTN; ++nt)
                    acc[mt][nt] = __builtin_amdgcn_mfma_f32_16x16x32_f16(af[mt], bf[nt], acc[mt][nt], 0, 0, 0);
        }
    }

    // ---------------- epilogue: dist + dual-sided batch-hard mining ----------
    float sqi[MTN][4]; int labi[MTN][4];
    #pragma unroll
    for (int mt = 0; mt < MTN; ++mt)
        #pragma unroll
        for (int rg = 0; rg < 4; ++rg) {
            int i = i0 + wi + mt * 16 + lq * 4 + rg;
            sqi[mt][rg] = sq[i];
            labi[mt][rg] = labels[i];
        }
    float sqj[NTN]; int labj[NTN];
    #pragma unroll
    for (int nt = 0; nt < NTN; ++nt) {
        int j = j0 + joff + wjL + nt * 16 + ln15;
        sqj[nt] = sq[j];
        labj[nt] = labels[j];
    }

    float api[MTN][4], ani[MTN][4], apj[NTN], anj[NTN];
    #pragma unroll
    for (int mt = 0; mt < MTN; ++mt)
        #pragma unroll
        for (int rg = 0; rg < 4; ++rg) { api[mt][rg] = -INFINITY; ani[mt][rg] = INFINITY; }
    #pragma unroll
    for (int nt = 0; nt < NTN; ++nt) { apj[nt] = -INFINITY; anj[nt] = INFINITY; }

    #pragma unroll
    for (int nt = 0; nt < NTN; ++nt) {
        int j = j0 + joff + wjL + nt * 16 + ln15;
        #pragma unroll
        for (int mt = 0; mt < MTN; ++mt)
            #pragma unroll
            for (int rg = 0; rg < 4; ++rg) {
                int i = i0 + wi + mt * 16 + lq * 4 + rg;
                float d2 = sqi[mt][rg] + sqj[nt] - 2.0f * acc[mt][nt][rg];
                float dist = sqrtf(fmaxf(d2, 0.0f) + 1e-12f);
                if (labi[mt][rg] == labj[nt]) {
                    if (i != j) {
                        api[mt][rg] = fmaxf(api[mt][rg], dist);
                        apj[nt]     = fmaxf(apj[nt], dist);
                    }
                } else {
                    ani[mt][rg] = fminf(ani[mt][rg], dist);
                    anj[nt]     = fminf(anj[nt], dist);
                }
            }
    }

    // i-side reduce over the 16 ln15-lanes
    #pragma unroll
    for (int mt = 0; mt < MTN; ++mt)
        #pragma unroll
        for (int rg = 0; rg < 4; ++rg) {
            float a_ = api[mt][rg], n_ = ani[mt][rg];
            #pragma unroll
            for (int off = 1; off < 16; off <<= 1) {
                a_ = fmaxf(a_, __shfl_xor(a_, off, 64));
                n_ = fminf(n_, __shfl_xor(n_, off, 64));
            }
            if (ln15 == 0) {
                int i = i0 + wi + mt * 16 + lq * 4 + rg;
                if (a_ > -1.0e37f) atomicMax(&ap_bits[i], __float_as_uint(a_));
                if (n_ <  1.0e37f) atomicMin(&an_bits[i], __float_as_uint(n_));
            }
        }

    // j-side reduce over the 4 lq-quads (skip on diagonal tiles: idempotent anyway)
    if (!diag) {
        #pragma unroll
        for (int nt = 0; nt < NTN; ++nt) {
            float a_ = apj[nt], n_ = anj[nt];
            #pragma unroll
            for (int off = 16; off < 64; off <<= 1) {
                a_ = fmaxf(a_, __shfl_xor(a_, off, 64));
                n_ = fminf(n_, __shfl_xor(n_, off, 64));
            }
            if (lq == 0) {
                int j = j0 + joff + wjL + nt * 16 + ln15;
                if (a_ > -1.0e37f) atomicMax(&ap_bits[j], __float_as_uint(a_));
                if (n_ <  1.0e37f) atomicMin(&an_bits[j], __float_as_uint(n_));
            }
        }
    }
}

// ------- Kernel 2: MFMA Gram + mining (balanced triangular) + finalize ------
__global__ __launch_bounds__(256) void mine_kernel(const _Float16* __restrict__ e,
                                                   const float* __restrict__ sq,
                                                   const int* __restrict__ labels,
                                                   unsigned* __restrict__ ap_bits,
                                                   unsigned* __restrict__ an_bits,
                                                   unsigned* __restrict__ counter,
                                                   float* __restrict__ out) {
    __shared__ unsigned short S[16384];  // A: 16 KB | B: 16 KB (BK=64)

    const int tid  = threadIdx.x;
    const int w    = tid >> 6;
    const int lane = tid & 63;

    // schedule: blocks 0..511 -> full tiles (linear 0..511);
    // blocks 512..575 -> tiles 512..527 split into 4 j-quarters of 32 cols.
    int t, jlo, small;
    if (blockIdx.x < 512) { t = blockIdx.x; jlo = 0; small = 0; }
    else { int s2 = blockIdx.x - 512; t = 512 + (s2 >> 2); jlo = (s2 & 3) * 32; small = 1; }

    int bi = 0, rem = t;
    while (rem >= 32 - bi) { rem -= 32 - bi; ++bi; }
    const int bj = bi + rem;
    const int i0 = bi * 128, j0 = bj * 128;

    if (!small)
        tile_work<4, 4, 128>(e, sq, labels, ap_bits, an_bits, S, i0, j0, 0,
                             (w & 1) * 64, (w >> 1) * 64, tid, w, lane, bi == bj);
    else
        tile_work<2, 2, 32>(e, sq, labels, ap_bits, an_bits, S, i0, j0, jlo,
                            w * 32, 0, tid, w, lane, bi == bj);

    // ---------------- last-block finalize ----------------
    __shared__ unsigned lastFlag;
    __shared__ int cnt[4];
    __shared__ float red[8];
    __threadfence();
    if (tid == 0) lastFlag = (atomicAdd(counter, 1u) == NBLK - 1) ? 1u : 0u;
    __syncthreads();
    if (!lastFlag) return;
    __threadfence();

    if (tid < 4) cnt[tid] = 0;
    __syncthreads();
    int local[4] = {0, 0, 0, 0};
    for (int i = tid; i < N; i += 256) local[labels[i] & 3]++;
    #pragma unroll
    for (int c = 0; c < 4; c++) atomicAdd(&cnt[c], local[c]);
    __syncthreads();

    float sum = 0.f, nv = 0.f;
    for (int i = tid; i < N; i += 256) {
        int l = labels[i] & 3;
        if (cnt[l] >= 2) {
            nv += 1.f;
            float apv = __uint_as_float(atomicAdd(&ap_bits[i], 0u));  // coherent read
            float anv = __uint_as_float(atomicAdd(&an_bits[i], 0u));
            if (anv < 3.0e38f) sum += fmaxf(apv - anv + MARGIN, 0.f);
        }
    }

    #pragma unroll
    for (int off = 32; off; off >>= 1) {
        sum += __shfl_down(sum, off, 64);
        nv  += __shfl_down(nv,  off, 64);
    }
    if ((tid & 63) == 0) { red[tid >> 6] = sum; red[4 + (tid >> 6)] = nv; }
    __syncthreads();
    if (tid == 0) {
        float s = red[0] + red[1] + red[2] + red[3];
        float n = red[4] + red[5] + red[6] + red[7];
        out[0] = s / fmaxf(n, 1.f);
    }
}

// ---------------- Launch ----------------
extern "C" void kernel_launch(void* const* d_in, const int* in_sizes, int n_in,
                              void* d_out, int out_size, void* d_ws, size_t ws_size,
                              hipStream_t stream) {
    const float* x = (const float*)d_in[0];
    const int* labels = (const int*)d_in[1];
    float* out = (float*)d_out;

    _Float16* e = (_Float16*)d_ws;
    float* sq = (float*)(e + (size_t)N * D);
    unsigned* ap_bits = (unsigned*)(sq + N);
    unsigned* an_bits = ap_bits + N;
    unsigned* counter = an_bits + N;

    normalize_kernel<<<N / 4, 256, 0, stream>>>(x, e, sq, ap_bits, an_bits, counter);
    mine_kernel<<<NBLK, 256, 0, stream>>>(e, sq, labels, ap_bits, an_bits, counter, out);
}

// Round 5
// 127.856 us; speedup vs baseline: 1.1462x; 1.1462x over previous
//
#include <hip/hip_runtime.h>
#include <math.h>

#define N 4096
#define D 768
#define MARGIN 1.0f
#define NBLK 576   // 512 full 128x128 tiles + 16 tiles split into 4x(128x32)

typedef _Float16 half8 __attribute__((ext_vector_type(8)));
typedef _Float16 half4 __attribute__((ext_vector_type(4)));
typedef float f32x4 __attribute__((ext_vector_type(4)));

__device__ __forceinline__ void gl2lds16(const void* g, void* l) {
    __builtin_amdgcn_global_load_lds((const __attribute__((address_space(1))) void*)g,
                                     (__attribute__((address_space(3))) void*)l, 16, 0, 0);
}

// ---------------- Kernel 1: row L2-normalize (wave-per-row) + init ----------
__global__ __launch_bounds__(256) void normalize_kernel(const float* __restrict__ x,
                                                        _Float16* __restrict__ e,
                                                        float* __restrict__ sq,
                                                        unsigned* __restrict__ ap_bits,
                                                        unsigned* __restrict__ an_bits,
                                                        unsigned* __restrict__ counter) {
    const int tid = threadIdx.x;
    const int wave = tid >> 6, lane = tid & 63;
    const int row = blockIdx.x * 4 + wave;

    const float4* xr = (const float4*)(x + (size_t)row * D);   // 192 float4/row
    float4 f0 = xr[lane];
    float4 f1 = xr[lane + 64];
    float4 f2 = xr[lane + 128];

    float s = f0.x*f0.x + f0.y*f0.y + f0.z*f0.z + f0.w*f0.w
            + f1.x*f1.x + f1.y*f1.y + f1.z*f1.z + f1.w*f1.w
            + f2.x*f2.x + f2.y*f2.y + f2.z*f2.z + f2.w*f2.w;
    #pragma unroll
    for (int off = 1; off < 64; off <<= 1) s += __shfl_xor(s, off, 64);

    float scale = 1.0f / fmaxf(sqrtf(s), 1e-12f);

    half4* er = (half4*)(e + (size_t)row * D);
    half4 h0 = { (_Float16)(f0.x*scale), (_Float16)(f0.y*scale), (_Float16)(f0.z*scale), (_Float16)(f0.w*scale) };
    half4 h1 = { (_Float16)(f1.x*scale), (_Float16)(f1.y*scale), (_Float16)(f1.z*scale), (_Float16)(f1.w*scale) };
    half4 h2 = { (_Float16)(f2.x*scale), (_Float16)(f2.y*scale), (_Float16)(f2.z*scale), (_Float16)(f2.w*scale) };
    er[lane]       = h0;
    er[lane + 64]  = h1;
    er[lane + 128] = h2;

    if (lane == 0) {
        sq[row] = s * scale * scale;
        ap_bits[row] = 0u;                 // float 0.0  (max init)
        an_bits[row] = 0x7f800000u;        // +inf       (min init)
    }
    if (blockIdx.x == 0 && tid == 0) *counter = 0u;
}

// ---------------- templated tile worker (BK=32, single-buffered) -----------
// LDS: A = S[0..4095] ushorts (128 rows x 32 halves, XOR-swizzled),
//      B = S[4096..8191] ushorts (BROWS rows x 32 halves).
template<int MTN, int NTN, int BROWS>
__device__ __forceinline__ void tile_work(const _Float16* __restrict__ e,
                                          const float* __restrict__ sq,
                                          const int* __restrict__ labels,
                                          unsigned* __restrict__ ap_bits,
                                          unsigned* __restrict__ an_bits,
                                          unsigned short* S,
                                          int i0, int jbase,
                                          int wi, int wjL,
                                          int tid, int w, int lane, bool diag) {
    const int ln15 = lane & 15;
    const int lq   = lane >> 4;       // 0..3

    f32x4 acc[MTN][NTN] = {};

    for (int kt = 0; kt < 24; ++kt) {
        const int k0 = kt * 32;
        __syncthreads();
        // stage A: 128 rows x 4 granules (16B) = 512 granules, 2 per thread
        #pragma unroll
        for (int p = 0; p < 2; ++p) {
            int s  = p * 256 + tid;
            int r  = s >> 2;
            int kg = (s & 3) ^ ((r >> 1) & 3);
            gl2lds16(e + (size_t)(i0 + r) * D + k0 + kg * 8,
                     (char*)S + (p * 256 + w * 64) * 16);
        }
        // stage B: BROWS rows x 4 granules
        if constexpr (BROWS == 128) {
            #pragma unroll
            for (int p = 0; p < 2; ++p) {
                int s  = p * 256 + tid;
                int r  = s >> 2;
                int kg = (s & 3) ^ ((r >> 1) & 3);
                gl2lds16(e + (size_t)(jbase + r) * D + k0 + kg * 8,
                         (char*)S + 8192 + (p * 256 + w * 64) * 16);
            }
        } else {  // 32 rows -> 128 granules, waves 0..1 only (wave-uniform branch)
            if (w < 2) {
                int s  = tid;                  // 0..127
                int r  = s >> 2;
                int kg = (s & 3) ^ ((r >> 1) & 3);
                gl2lds16(e + (size_t)(jbase + r) * D + k0 + kg * 8,
                         (char*)S + 8192 + (w * 64) * 16);
            }
        }
        __syncthreads();

        half8 af[MTN], bf[NTN];
        #pragma unroll
        for (int mt = 0; mt < MTN; ++mt) {
            int r  = wi + mt * 16 + ln15;
            int kx = lq ^ ((r >> 1) & 3);
            af[mt] = *(const half8*)&S[r * 32 + kx * 8];
        }
        #pragma unroll
        for (int nt = 0; nt < NTN; ++nt) {
            int r  = wjL + nt * 16 + ln15;
            int kx = lq ^ ((r >> 1) & 3);
            bf[nt] = *(const half8*)&S[4096 + r * 32 + kx * 8];
        }
        #pragma unroll
        for (int mt = 0; mt < MTN; ++mt)
            #pragma unroll
            for (int nt = 0; nt < NTN; ++nt)
                acc[mt][nt] = __builtin_amdgcn_mfma_f32_16x16x32_f16(af[mt], bf[nt], acc[mt][nt], 0, 0, 0);
    }

    // ---------------- epilogue: dist + dual-sided batch-hard mining ----------
    float sqi[MTN][4]; int labi[MTN][4];
    #pragma unroll
    for (int mt = 0; mt < MTN; ++mt)
        #pragma unroll
        for (int rg = 0; rg < 4; ++rg) {
            int i = i0 + wi + mt * 16 + lq * 4 + rg;
            sqi[mt][rg] = sq[i];
            labi[mt][rg] = labels[i];
        }
    float sqj[NTN]; int labj[NTN];
    #pragma unroll
    for (int nt = 0; nt < NTN; ++nt) {
        int j = jbase + wjL + nt * 16 + ln15;
        sqj[nt] = sq[j];
        labj[nt] = labels[j];
    }

    float api[MTN][4], ani[MTN][4], apj[NTN], anj[NTN];
    #pragma unroll
    for (int mt = 0; mt < MTN; ++mt)
        #pragma unroll
        for (int rg = 0; rg < 4; ++rg) { api[mt][rg] = -INFINITY; ani[mt][rg] = INFINITY; }
    #pragma unroll
    for (int nt = 0; nt < NTN; ++nt) { apj[nt] = -INFINITY; anj[nt] = INFINITY; }

    #pragma unroll
    for (int nt = 0; nt < NTN; ++nt) {
        int j = jbase + wjL + nt * 16 + ln15;
        #pragma unroll
        for (int mt = 0; mt < MTN; ++mt)
            #pragma unroll
            for (int rg = 0; rg < 4; ++rg) {
                int i = i0 + wi + mt * 16 + lq * 4 + rg;
                float d2 = sqi[mt][rg] + sqj[nt] - 2.0f * acc[mt][nt][rg];
                float dist = sqrtf(fmaxf(d2, 0.0f) + 1e-12f);
                if (labi[mt][rg] == labj[nt]) {
                    if (i != j) {
                        api[mt][rg] = fmaxf(api[mt][rg], dist);
                        apj[nt]     = fmaxf(apj[nt], dist);
                    }
                } else {
                    ani[mt][rg] = fminf(ani[mt][rg], dist);
                    anj[nt]     = fminf(anj[nt], dist);
                }
            }
    }

    // i-side reduce over the 16 ln15-lanes
    #pragma unroll
    for (int mt = 0; mt < MTN; ++mt)
        #pragma unroll
        for (int rg = 0; rg < 4; ++rg) {
            float a_ = api[mt][rg], n_ = ani[mt][rg];
            #pragma unroll
            for (int off = 1; off < 16; off <<= 1) {
                a_ = fmaxf(a_, __shfl_xor(a_, off, 64));
                n_ = fminf(n_, __shfl_xor(n_, off, 64));
            }
            if (ln15 == 0) {
                int i = i0 + wi + mt * 16 + lq * 4 + rg;
                if (a_ > -1.0e37f) atomicMax(&ap_bits[i], __float_as_uint(a_));
                if (n_ <  1.0e37f) atomicMin(&an_bits[i], __float_as_uint(n_));
            }
        }

    // j-side reduce over the 4 lq-quads (skip on diagonal tiles — i-side covers them)
    if (!diag) {
        #pragma unroll
        for (int nt = 0; nt < NTN; ++nt) {
            float a_ = apj[nt], n_ = anj[nt];
            #pragma unroll
            for (int off = 16; off < 64; off <<= 1) {
                a_ = fmaxf(a_, __shfl_xor(a_, off, 64));
                n_ = fminf(n_, __shfl_xor(n_, off, 64));
            }
            if (lq == 0) {
                int j = jbase + wjL + nt * 16 + ln15;
                if (a_ > -1.0e37f) atomicMax(&ap_bits[j], __float_as_uint(a_));
                if (n_ <  1.0e37f) atomicMin(&an_bits[j], __float_as_uint(n_));
            }
        }
    }
}

// ------- Kernel 2: MFMA Gram + mining (balanced triangular) + finalize ------
__global__ __launch_bounds__(256) void mine_kernel(const _Float16* __restrict__ e,
                                                   const float* __restrict__ sq,
                                                   const int* __restrict__ labels,
                                                   unsigned* __restrict__ ap_bits,
                                                   unsigned* __restrict__ an_bits,
                                                   unsigned* __restrict__ counter,
                                                   float* __restrict__ out) {
    __shared__ unsigned short S[8192];  // A: 8 KB | B: 8 KB (BK=32)

    const int tid  = threadIdx.x;
    const int w    = tid >> 6;
    const int lane = tid & 63;

    // schedule: blocks 0..511 -> full tiles; 512..575 -> tiles 512..527 split
    // into 4 j-quarters of 32 columns each.
    int t, jlo, small;
    if (blockIdx.x < 512) { t = blockIdx.x; jlo = 0; small = 0; }
    else { int s2 = blockIdx.x - 512; t = 512 + (s2 >> 2); jlo = (s2 & 3) * 32; small = 1; }

    int bi = 0, rem = t;
    while (rem >= 32 - bi) { rem -= 32 - bi; ++bi; }
    const int bj = bi + rem;
    const int i0 = bi * 128, j0 = bj * 128;

    if (!small)
        tile_work<4, 4, 128>(e, sq, labels, ap_bits, an_bits, S, i0, j0,
                             (w & 1) * 64, (w >> 1) * 64, tid, w, lane, bi == bj);
    else
        tile_work<2, 2, 32>(e, sq, labels, ap_bits, an_bits, S, i0, j0 + jlo,
                            w * 32, 0, tid, w, lane, bi == bj);

    // ---------------- last-block finalize (scoped sync — no global cache nuke) ----
    __shared__ unsigned lastFlag;
    __syncthreads();   // each wave's s_waitcnt vmcnt(0) before barrier drains its atomics
    if (tid == 0) {
        __builtin_amdgcn_fence(__ATOMIC_RELEASE, "agent");   // wbl2 only; ~no dirty data
        lastFlag = (atomicAdd(counter, 1u) == NBLK - 1) ? 1u : 0u;
    }
    __syncthreads();
    if (!lastFlag) return;
    __builtin_amdgcn_fence(__ATOMIC_ACQUIRE, "agent");       // one block: inv L1/L2 once

    __shared__ int cnt[4];
    __shared__ float red[8];
    if (tid < 4) cnt[tid] = 0;
    __syncthreads();
    int local[4] = {0, 0, 0, 0};
    for (int i = tid; i < N; i += 256) local[labels[i] & 3]++;
    #pragma unroll
    for (int c = 0; c < 4; c++) atomicAdd(&cnt[c], local[c]);
    __syncthreads();

    float sum = 0.f, nv = 0.f;
    for (int i = tid; i < N; i += 256) {
        int l = labels[i] & 3;
        if (cnt[l] >= 2) {
            nv += 1.f;
            float apv = __uint_as_float(ap_bits[i]);   // plain loads: caches inv'd above
            float anv = __uint_as_float(an_bits[i]);
            if (anv < 3.0e38f) sum += fmaxf(apv - anv + MARGIN, 0.f);
        }
    }

    #pragma unroll
    for (int off = 32; off; off >>= 1) {
        sum += __shfl_down(sum, off, 64);
        nv  += __shfl_down(nv,  off, 64);
    }
    if ((tid & 63) == 0) { red[tid >> 6] = sum; red[4 + (tid >> 6)] = nv; }
    __syncthreads();
    if (tid == 0) {
        float s = red[0] + red[1] + red[2] + red[3];
        float n = red[4] + red[5] + red[6] + red[7];
        out[0] = s / fmaxf(n, 1.f);
    }
}

// ---------------- Launch ----------------
extern "C" void kernel_launch(void* const* d_in, const int* in_sizes, int n_in,
                              void* d_out, int out_size, void* d_ws, size_t ws_size,
                              hipStream_t stream) {
    const float* x = (const float*)d_in[0];
    const int* labels = (const int*)d_in[1];
    float* out = (float*)d_out;

    _Float16* e = (_Float16*)d_ws;
    float* sq = (float*)(e + (size_t)N * D);
    unsigned* ap_bits = (unsigned*)(sq + N);
    unsigned* an_bits = ap_bits + N;
    unsigned* counter = an_bits + N;

    normalize_kernel<<<N / 4, 256, 0, stream>>>(x, e, sq, ap_bits, an_bits, counter);
    mine_kernel<<<NBLK, 256, 0, stream>>>(e, sq, labels, ap_bits, an_bits, counter, out);
}